// Round 16
// baseline (87.504 us; speedup 1.0000x reference)
//
#include <hip/hip_runtime.h>
#include <hip/hip_bf16.h>
#include <cstdint>
#include <cstddef>

#define DIMC 1024
#define HEADS 16
#define HD 64
#define WINDOW 128
#define BB 2
#define TT 2048
#define NTOK (BB*TT)       // 4096
#define QKVN (3*DIMC)      // 3072

typedef __bf16 bf16;
typedef __bf16 bf16x8 __attribute__((ext_vector_type(8)));
typedef __bf16 bf16x4 __attribute__((ext_vector_type(4)));
typedef float f32x4 __attribute__((ext_vector_type(4)));
typedef float float4v __attribute__((ext_vector_type(4)));
typedef unsigned int u32;

typedef const __attribute__((address_space(1))) u32* gp1_t;
typedef __attribute__((address_space(3))) u32* lp3_t;

__device__ __forceinline__ void gload16(const void* g, void* l) {
  __builtin_amdgcn_global_load_lds((gp1_t)g, (lp3_t)l, 16, 0, 0);
}

__device__ __forceinline__ u32 lds_u32(const void* p) {
  return (u32)(uintptr_t)(__attribute__((address_space(3))) const void*)p;
}

__device__ __forceinline__ void BAR() {
  asm volatile("" ::: "memory");
  __builtin_amdgcn_s_barrier();
  asm volatile("" ::: "memory");
}

// ---------------------------------------------------------------- cast kernel (x only now)
__global__ void castx_kernel(const float* __restrict__ x,
                             bf16* __restrict__ xo) {
  const int NX = NTOK * DIMC / 4;
  for (int i = blockIdx.x * blockDim.x + threadIdx.x; i < NX;
       i += gridDim.x * blockDim.x) {
    float4v v = ((const float4v*)x)[i];
    bf16x4 o;
    o[0] = (bf16)v[0]; o[1] = (bf16)v[1]; o[2] = (bf16)v[2]; o[3] = (bf16)v[3];
    ((bf16x4*)xo)[i] = o;
  }
}

__device__ __forceinline__ bf16x8 lds_frag(const bf16* base, int row, int colb) {
  const char* p = (const char*)base + row * 128 + (colb ^ ((row & 7) << 4));
  return *(const bf16x8*)p;
}

// ---------------------------------------------------------------- QKV GEMM: 128x192, 8 waves (2M x 4N)
// R12/R14 schedule, but B staged from fp32 Wqkv via reg-staging:
// global_load fp32 -> cvt bf16 -> swizzled ds_write_b128 (fused weight cast).
__global__ __launch_bounds__(512, 2) void gemm_qkv_kernel(
    const bf16* __restrict__ A, const float* __restrict__ Wq,
    bf16* __restrict__ C) {
  constexpr int NT = 16;
  __shared__ bf16 Al[2][128 * 64];
  __shared__ bf16 Bl[2][192 * 64];

  const int tid = threadIdx.x;
  const int w = tid >> 6, l = tid & 63;
  const int wm = w >> 2, wn = w & 3;   // 2M x 4N
  const int lr = l & 15, lg = l >> 4;

  const int bid = blockIdx.x;
  const int x = bid & 7, i = bid >> 3;
  const int bm = 8 * (x >> 1) + (i & 7);
  const int bn = 8 * (x & 1) + (i >> 3);

  const char* Ag = (const char*)A + (size_t)(bm * 128) * 2048;
  const float* Bg = Wq + (size_t)(bn * 192) * 1024;

  auto stageA = [&](bf16* lds, int kt) {
#pragma unroll
    for (int i2 = 0; i2 < 2; i2++) {
      const int R0 = w * 16 + i2 * 8;
      const int r = R0 + (l >> 3);
      const char* src = Ag + (size_t)r * 2048 + kt * 128
                        + (((l & 7) * 16) ^ ((r & 7) << 4));
      gload16(src, lds + R0 * 64);
    }
  };

  // B reg-staging: 24 rows/wave, lane covers 8 fp32 cols of one row per group
  float br[24];
  auto loadB = [&](int kt) {
#pragma unroll
    for (int i2 = 0; i2 < 3; i2++) {
      const int r = w * 24 + i2 * 8 + (l >> 3);
      const float* src = Bg + (size_t)r * 1024 + kt * 64 + (l & 7) * 8;
      float4v v0 = *(const float4v*)src;
      float4v v1 = *(const float4v*)(src + 4);
#pragma unroll
      for (int e = 0; e < 4; e++) { br[i2 * 8 + e] = v0[e]; br[i2 * 8 + 4 + e] = v1[e]; }
    }
  };
  auto writeB = [&](bf16* lds) {
#pragma unroll
    for (int i2 = 0; i2 < 3; i2++) {
      const int r = w * 24 + i2 * 8 + (l >> 3);
      bf16x8 o;
#pragma unroll
      for (int e = 0; e < 8; e++) o[e] = (bf16)br[i2 * 8 + e];
      *(bf16x8*)((char*)lds + r * 128 + (((l & 7) * 16) ^ ((r & 7) << 4))) = o;
    }
  };

  // prologue (serial B0 then B1 to cap VGPR at one 24-reg buffer)
  loadB(0);
  stageA(Al[0], 0); stageA(Al[1], 1);
  asm volatile("s_waitcnt vmcnt(4)" ::: "memory");   // B0 done (A0,A1 outstanding)
  writeB(Bl[0]);
  loadB(1);
  asm volatile("s_waitcnt vmcnt(8)" ::: "memory");   // A0 done (A1 + B1 outstanding)
  asm volatile("s_waitcnt lgkmcnt(0)" ::: "memory"); // B0 writes drained
  BAR();

  f32x4 acc[4][3] = {};

  for (int kt = 0; kt < NT; ++kt) {
    const bf16* Ac = Al[kt & 1];
    const bf16* Bc = Bl[kt & 1];

    bf16x8 af[4][2], bf[3][2];
#pragma unroll
    for (int m = 0; m < 4; m++)
#pragma unroll
      for (int kk = 0; kk < 2; kk++)
        af[m][kk] = lds_frag(Ac, wm * 64 + m * 16 + lr, kk * 64 + lg * 16);
#pragma unroll
    for (int n = 0; n < 3; n++)
#pragma unroll
      for (int kk = 0; kk < 2; kk++)
        bf[n][kk] = lds_frag(Bc, wn * 48 + n * 16 + lr, kk * 64 + lg * 16);

    asm volatile("s_waitcnt lgkmcnt(0)" ::: "memory");
    __builtin_amdgcn_sched_barrier(0);
    BAR();

    if (kt + 2 < NT) stageA(Al[kt & 1], kt + 2);
    if (kt + 1 < NT) {
      if (kt + 2 < NT) asm volatile("s_waitcnt vmcnt(2)" ::: "memory");
      else             asm volatile("s_waitcnt vmcnt(0)" ::: "memory");
      writeB(Bl[(kt + 1) & 1]);
    }
    if (kt + 2 < NT) loadB(kt + 2);

    __builtin_amdgcn_s_setprio(1);
#pragma unroll
    for (int kk = 0; kk < 2; kk++)
#pragma unroll
      for (int m = 0; m < 4; m++)
#pragma unroll
        for (int n = 0; n < 3; n++)
          acc[m][n] = __builtin_amdgcn_mfma_f32_16x16x32_bf16(
              af[m][kk], bf[n][kk], acc[m][n], 0, 0, 0);
    __builtin_amdgcn_s_setprio(0);

    asm volatile("s_waitcnt lgkmcnt(0)" ::: "memory");  // drain B writes
    BAR();
  }

#pragma unroll
  for (int m = 0; m < 4; m++) {
    const int row = bm * 128 + wm * 64 + m * 16 + lg * 4;
#pragma unroll
    for (int n = 0; n < 3; n++) {
      const int col = bn * 192 + wn * 48 + n * 16 + lr;
#pragma unroll
      for (int j = 0; j < 4; j++)
        C[(size_t)(row + j) * QKVN + col] = (bf16)acc[m][n][j];
    }
  }
}

// ---------------------------------------------------------------- proj GEMM: 128x64, 8 waves (4M x 2N)
// B staged from fp32 Wproj via reg-staging (fused weight cast).
__global__ __launch_bounds__(512, 2) void gemm_proj_kernel(
    const bf16* __restrict__ A, const float* __restrict__ Wp,
    float* __restrict__ Cf, const float* __restrict__ bias) {
  constexpr int NT = 16;
  __shared__ bf16 Al[2][128 * 64];
  __shared__ bf16 Bl[2][64 * 64];

  const int tid = threadIdx.x;
  const int w = tid >> 6, l = tid & 63;
  const int wm = w >> 1, wn = w & 1;   // 4M x 2N
  const int lr = l & 15, lg = l >> 4;

  const int bid = blockIdx.x;
  const int x = bid & 7, i = bid >> 3;
  const int bm = 8 * (x >> 1) + (i & 7);
  const int bn = 8 * (x & 1) + (i >> 3);

  const char* Ag = (const char*)A + (size_t)(bm * 128) * 2048;
  const float* Bg = Wp + (size_t)(bn * 64) * 1024;

  auto stageA = [&](bf16* lds, int kt) {
#pragma unroll
    for (int i2 = 0; i2 < 2; i2++) {
      const int R0 = w * 16 + i2 * 8;
      const int r = R0 + (l >> 3);
      const char* src = Ag + (size_t)r * 2048 + kt * 128
                        + (((l & 7) * 16) ^ ((r & 7) << 4));
      gload16(src, lds + R0 * 64);
    }
  };

  float br[8];
  auto loadB = [&](int kt) {
    const int r = w * 8 + (l >> 3);
    const float* src = Bg + (size_t)r * 1024 + kt * 64 + (l & 7) * 8;
    float4v v0 = *(const float4v*)src;
    float4v v1 = *(const float4v*)(src + 4);
#pragma unroll
    for (int e = 0; e < 4; e++) { br[e] = v0[e]; br[4 + e] = v1[e]; }
  };
  auto writeB = [&](bf16* lds) {
    const int r = w * 8 + (l >> 3);
    bf16x8 o;
#pragma unroll
    for (int e = 0; e < 8; e++) o[e] = (bf16)br[e];
    *(bf16x8*)((char*)lds + r * 128 + (((l & 7) * 16) ^ ((r & 7) << 4))) = o;
  };

  loadB(0);
  stageA(Al[0], 0); stageA(Al[1], 1);
  asm volatile("s_waitcnt vmcnt(4)" ::: "memory");   // B0 done
  writeB(Bl[0]);
  loadB(1);
  asm volatile("s_waitcnt vmcnt(4)" ::: "memory");   // A0 done (A1 + B1 outstanding)
  asm volatile("s_waitcnt lgkmcnt(0)" ::: "memory");
  BAR();

  f32x4 acc[2][2] = {};

  for (int kt = 0; kt < NT; ++kt) {
    const bf16* Ac = Al[kt & 1];
    const bf16* Bc = Bl[kt & 1];

    bf16x8 af[2][2], bf[2][2];
#pragma unroll
    for (int m = 0; m < 2; m++)
#pragma unroll
      for (int kk = 0; kk < 2; kk++)
        af[m][kk] = lds_frag(Ac, wm * 32 + m * 16 + lr, kk * 64 + lg * 16);
#pragma unroll
    for (int n = 0; n < 2; n++)
#pragma unroll
      for (int kk = 0; kk < 2; kk++)
        bf[n][kk] = lds_frag(Bc, wn * 32 + n * 16 + lr, kk * 64 + lg * 16);

    asm volatile("s_waitcnt lgkmcnt(0)" ::: "memory");
    __builtin_amdgcn_sched_barrier(0);
    BAR();

    if (kt + 2 < NT) stageA(Al[kt & 1], kt + 2);
    if (kt + 1 < NT) {
      if (kt + 2 < NT) asm volatile("s_waitcnt vmcnt(2)" ::: "memory");
      else             asm volatile("s_waitcnt vmcnt(0)" ::: "memory");
      writeB(Bl[(kt + 1) & 1]);
    }
    if (kt + 2 < NT) loadB(kt + 2);

    __builtin_amdgcn_s_setprio(1);
#pragma unroll
    for (int kk = 0; kk < 2; kk++)
#pragma unroll
      for (int m = 0; m < 2; m++)
#pragma unroll
        for (int n = 0; n < 2; n++)
          acc[m][n] = __builtin_amdgcn_mfma_f32_16x16x32_bf16(
              af[m][kk], bf[n][kk], acc[m][n], 0, 0, 0);
    __builtin_amdgcn_s_setprio(0);

    asm volatile("s_waitcnt lgkmcnt(0)" ::: "memory");
    BAR();
  }

#pragma unroll
  for (int m = 0; m < 2; m++) {
    const int row = bm * 128 + wm * 32 + m * 16 + lg * 4;
#pragma unroll
    for (int n = 0; n < 2; n++) {
      const int col = bn * 64 + wn * 32 + n * 16 + lr;
#pragma unroll
      for (int j = 0; j < 4; j++)
        Cf[(size_t)(row + j) * DIMC + col] = acc[m][n][j] + bias[col];
    }
  }
}

// ---------------------------------------------------------------- attention v4 (R14 config, unchanged)
__global__ __launch_bounds__(512, 4) void attn_kernel(const bf16* __restrict__ qkv,
                                                      bf16* __restrict__ out) {
  __shared__ bf16 Kl[3][64 * 64];
  __shared__ bf16 Vl[3][64 * 64];

  const int tid = threadIdx.x, w = tid >> 6, l = tid & 63;
  const int bid = blockIdx.x;
  const int x = bid & 7, ii = bid >> 3;
  const int bh = x * 4 + (ii >> 4);
  const int qb = ii & 15;
  const int b = bh >> 4, h = bh & 15;
  const int q0 = qb * 128;
  const int lr = l & 15, lg = l >> 4;
  const float SC = 0.18033688011f;   // 0.125 * log2(e)

  const char* qkv_b = (const char*)qkv + (size_t)(b * TT) * (QKVN * 2);

  size_t koff; u32 kdst;
  {
    const int R0 = 8 * w;
    const int r = R0 + (l >> 3);
    const int colb = (((l & 7) * 16) ^ (((l >> 3) & 7) << 4));
    koff = (size_t)r * (QKVN * 2) + (DIMC + h * HD) * 2 + colb;
    kdst = (u32)(R0 * 64);
  }
  size_t voff; u32 vdst;
  {
    const int c = tid;
    const int t = c >> 3, w_ = c & 7;
    const int kv = (t & 15) * 4 + (w_ >> 1);
    const int d  = (t >> 4) * 16 + (w_ & 1) * 8;
    voff = (size_t)kv * (QKVN * 2) + (2 * DIMC + h * HD + d) * 2;
    vdst = (u32)(w * 512);
  }

  auto stage = [&](int buf, int kb) {
    const char* rowb = qkv_b + (size_t)(kb * 64) * (QKVN * 2);
    gload16(rowb + koff, &Kl[buf][kdst]);
    gload16(rowb + voff, &Vl[buf][vdst]);
  };

  bf16x8 qf[2];
  {
    const bf16* qp = qkv + (size_t)(b * TT + q0 + w * 16 + lr) * QKVN + h * HD + lg * 8;
    qf[0] = *(const bf16x8*)qp;
    qf[1] = *(const bf16x8*)(qp + 32);
  }

  f32x4 Oa[4] = {};
  float mrow = -1e30f, lrow = 0.f;

  int kb0 = 2 * qb - 2; if (kb0 < 0) kb0 = 0;
  int kb1 = 2 * qb + 3; if (kb1 > 31) kb1 = 31;

  stage(0, kb0);
  stage(1, kb0 + 1);
  asm volatile("s_waitcnt vmcnt(2)" ::: "memory");
  BAR();

  for (int kb = kb0; kb <= kb1; ++kb) {
    const int c = (kb - kb0) % 3;
    if (kb + 2 <= kb1) stage((c + 2) % 3, kb + 2);

    const bf16* Kb = &Kl[c][0];
    f32x4 Sa[4] = {};
#pragma unroll
    for (int kf = 0; kf < 2; kf++)
#pragma unroll
      for (int nf = 0; nf < 4; nf++) {
        const char* kp = (const char*)Kb + (nf * 16 + lr) * 128
                         + ((kf * 64 + lg * 16) ^ ((lr & 7) << 4));
        bf16x8 kfr = *(const bf16x8*)kp;
        Sa[nf] = __builtin_amdgcn_mfma_f32_16x16x32_bf16(kfr, qf[kf], Sa[nf], 0, 0, 0);
      }

    bf16x4 tr0[4][2], tr1[4][2];
    {
      const u32 vbase = lds_u32(&Vl[c][0]) + l * 8;
#pragma unroll
      for (int nf = 0; nf < 4; nf++)
#pragma unroll
        for (int kf = 0; kf < 2; kf++) {
          const u32 a = vbase + (u32)((nf * 16 + kf * 8) * 128);
          asm volatile("ds_read_b64_tr_b16 %0, %1"
                       : "=v"(tr0[nf][kf]) : "v"(a));
          asm volatile("ds_read_b64_tr_b16 %0, %1 offset:512"
                       : "=v"(tr1[nf][kf]) : "v"(a));
        }
    }

    const int kvb = kb * 64;
    const int qrow = q0 + w * 16 + lr;
    float mblk = -1e30f;
#pragma unroll
    for (int nf = 0; nf < 4; nf++)
#pragma unroll
      for (int j = 0; j < 4; j++) {
        int kv = kvb + nf * 16 + lg * 4 + j;
        int dq = qrow - kv;
        float s = Sa[nf][j] * SC;
        if (dq > WINDOW || dq < -WINDOW) s = -1e30f;
        Sa[nf][j] = s;
        mblk = fmaxf(mblk, s);
      }
    mblk = fmaxf(mblk, __shfl_xor(mblk, 16));
    mblk = fmaxf(mblk, __shfl_xor(mblk, 32));

    if (!__all(mblk <= mrow + 8.f)) {
      float mn = fmaxf(mrow, mblk);
      float sc = exp2f(mrow - mn);
      mrow = mn;
      lrow *= sc;
#pragma unroll
      for (int j = 0; j < 4; j++) {
        float so = __shfl(sc, lg * 4 + j);
#pragma unroll
        for (int nf = 0; nf < 4; nf++) Oa[nf][j] *= so;
      }
    }

    float rsum = 0.f;
#pragma unroll
    for (int nf = 0; nf < 4; nf++)
#pragma unroll
      for (int j = 0; j < 4; j++) {
        float e = exp2f(Sa[nf][j] - mrow);
        Sa[nf][j] = e;
        rsum += e;
      }
    rsum += __shfl_xor(rsum, 16);
    rsum += __shfl_xor(rsum, 32);
    lrow += rsum;

    bf16x8 pa[2];
#pragma unroll
    for (int kf = 0; kf < 2; kf++)
#pragma unroll
      for (int e = 0; e < 4; e++) {
        pa[kf][e]     = (bf16)Sa[2 * kf][e];
        pa[kf][e + 4] = (bf16)Sa[2 * kf + 1][e];
      }

    asm volatile("s_waitcnt lgkmcnt(0)" ::: "memory");
    __builtin_amdgcn_sched_barrier(0);
#pragma unroll
    for (int nf = 0; nf < 4; nf++)
#pragma unroll
      for (int kf = 0; kf < 2; kf++) {
        bf16x8 vb;
#pragma unroll
        for (int e = 0; e < 4; e++) {
          vb[e]     = tr0[nf][kf][e];
          vb[e + 4] = tr1[nf][kf][e];
        }
        Oa[nf] = __builtin_amdgcn_mfma_f32_16x16x32_bf16(pa[kf], vb, Oa[nf], 0, 0, 0);
      }

    if (kb < kb1) {
      if (kb + 2 <= kb1) asm volatile("s_waitcnt vmcnt(2)" ::: "memory");
      else               asm volatile("s_waitcnt vmcnt(0)" ::: "memory");
    }
    BAR();
  }

  float lo[4];
#pragma unroll
  for (int j = 0; j < 4; j++) lo[j] = __shfl(lrow, lg * 4 + j);
#pragma unroll
  for (int nf = 0; nf < 4; nf++) {
#pragma unroll
    for (int j = 0; j < 4; j++) {
      int q = q0 + w * 16 + lg * 4 + j;
      int d = nf * 16 + lr;
      out[(size_t)(b * TT + q) * DIMC + h * HD + d] = (bf16)(Oa[nf][j] / lo[j]);
    }
  }
}

// ---------------------------------------------------------------- launch
extern "C" void kernel_launch(void* const* d_in, const int* in_sizes, int n_in,
                              void* d_out, int out_size, void* d_ws, size_t ws_size,
                              hipStream_t stream) {
  const float* x     = (const float*)d_in[0];
  const float* Wqkv  = (const float*)d_in[1];
  const float* Wproj = (const float*)d_in[2];
  const float* bproj = (const float*)d_in[3];
  float* out = (float*)d_out;

  char* ws = (char*)d_ws;
  bf16* xb   = (bf16*)(ws);                 // 8388608 B
  bf16* qkvb = (bf16*)(ws + 8388608);       // 25165824 B
  bf16* aob  = (bf16*)(ws + 33554432);      // 8388608 B

  castx_kernel<<<1024, 256, 0, stream>>>(x, xb);
  gemm_qkv_kernel<<<512, 512, 0, stream>>>(xb, Wqkv, qkvb);
  attn_kernel<<<512, 512, 0, stream>>>(qkvb, aob);
  gemm_proj_kernel<<<512, 512, 0, stream>>>(aob, Wproj, out, bproj);
}

// Round 17
// 75.306 us; speedup vs baseline: 1.1620x; 1.1620x over previous
//
#include <hip/hip_runtime.h>
#include <hip/hip_bf16.h>
#include <cstdint>
#include <cstddef>

#define DIMC 1024
#define HEADS 16
#define HD 64
#define WINDOW 128
#define BB 2
#define TT 2048
#define NTOK (BB*TT)       // 4096
#define QKVN (3*DIMC)      // 3072

typedef __bf16 bf16;
typedef __bf16 bf16x8 __attribute__((ext_vector_type(8)));
typedef __bf16 bf16x4 __attribute__((ext_vector_type(4)));
typedef float f32x4 __attribute__((ext_vector_type(4)));
typedef unsigned int u32;

typedef const __attribute__((address_space(1))) u32* gp1_t;
typedef __attribute__((address_space(3))) u32* lp3_t;

__device__ __forceinline__ void gload16(const void* g, void* l) {
  __builtin_amdgcn_global_load_lds((gp1_t)g, (lp3_t)l, 16, 0, 0);
}

__device__ __forceinline__ u32 lds_u32(const void* p) {
  return (u32)(uintptr_t)(__attribute__((address_space(3))) const void*)p;
}

__device__ __forceinline__ void BAR() {
  asm volatile("" ::: "memory");
  __builtin_amdgcn_s_barrier();
  asm volatile("" ::: "memory");
}

// ---------------------------------------------------------------- cast kernel
__global__ void cast3_kernel(const float* __restrict__ x,
                             const float* __restrict__ wq,
                             const float* __restrict__ wp,
                             bf16* __restrict__ xo,
                             bf16* __restrict__ wqo,
                             bf16* __restrict__ wpo) {
  const int NX = NTOK * DIMC / 4;
  const int NQ = QKVN * DIMC / 4;
  const int NP = DIMC * DIMC / 4;
  const int total = NX + NQ + NP;
  typedef float float4v __attribute__((ext_vector_type(4)));
  for (int i = blockIdx.x * blockDim.x + threadIdx.x; i < total;
       i += gridDim.x * blockDim.x) {
    const float4v* src; bf16* dst; int j;
    if (i < NX)            { src = (const float4v*)x;  dst = xo;  j = i; }
    else if (i < NX + NQ)  { src = (const float4v*)wq; dst = wqo; j = i - NX; }
    else                   { src = (const float4v*)wp; dst = wpo; j = i - NX - NQ; }
    float4v v = src[j];
    bf16x4 o;
    o[0] = (bf16)v[0]; o[1] = (bf16)v[1]; o[2] = (bf16)v[2]; o[3] = (bf16)v[3];
    ((bf16x4*)dst)[j] = o;
  }
}

// ---------------------------------------------------------------- 128xBN GEMM (C = A * B^T), 8 waves  [R12 config]
// BK=64, 8 waves (2M x 4N; wave = 64 x BN/4), double-buffered LDS, counted
// vmcnt(LPT), both-sides swizzle, 2D XCD blocking. Grid = 512 = exactly
// 2 blocks/CU co-resident (4 waves/SIMD), one dispatch round, no tail.
__device__ __forceinline__ bf16x8 lds_frag(const bf16* base, int row, int colb) {
  const char* p = (const char*)base + row * 128 + (colb ^ ((row & 7) << 4));
  return *(const bf16x8*)p;
}

template<int BN, int N_, bool BF16OUT>
__global__ __launch_bounds__(512, 2) void gemm_kernel(
    const bf16* __restrict__ A, const bf16* __restrict__ Bw,
    bf16* __restrict__ Cb, float* __restrict__ Cf,
    const float* __restrict__ bias) {
  constexpr int NT = 16;               // K=1024 / BK=64
  constexpr int NB = BN / 64;          // B frags per wave
  constexpr int LPT = 2 + NB;          // vmem issues per wave per K-tile
  __shared__ bf16 Al[2][128 * 64];
  __shared__ bf16 Bl[2][BN * 64];

  const int tid = threadIdx.x;
  const int w = tid >> 6, l = tid & 63;
  const int wm = w >> 2, wn = w & 3;   // 2M x 4N
  const int lr = l & 15, lg = l >> 4;

  // 2D XCD map: 8 regions of (8 bm x 8 bn); Nb = N_/BN = 16 for both GEMMs.
  const int bid = blockIdx.x;
  const int x = bid & 7, i = bid >> 3;
  const int bm = 8 * (x >> 1) + (i & 7);
  const int bn = 8 * (x & 1) + (i >> 3);

  const char* Ag = (const char*)A + (size_t)(bm * 128) * 2048;
  const char* Bg = (const char*)Bw + (size_t)(bn * BN) * 2048;

  auto stageA = [&](bf16* lds, int kt) {
#pragma unroll
    for (int i2 = 0; i2 < 2; i2++) {
      const int R0 = w * 16 + i2 * 8;
      const int r = R0 + (l >> 3);
      const char* src = Ag + (size_t)r * 2048 + kt * 128
                        + (((l & 7) * 16) ^ ((r & 7) << 4));
      gload16(src, lds + R0 * 64);
    }
  };
  auto stageB = [&](bf16* lds, int kt) {
#pragma unroll
    for (int i2 = 0; i2 < NB; i2++) {
      const int R0 = w * (BN / 8) + i2 * 8;
      const int r = R0 + (l >> 3);
      const char* src = Bg + (size_t)r * 2048 + kt * 128
                        + (((l & 7) * 16) ^ ((r & 7) << 4));
      gload16(src, lds + R0 * 64);
    }
  };

  auto waitLPT = [&]() {
    if constexpr (LPT == 5)      asm volatile("s_waitcnt vmcnt(5)" ::: "memory");
    else if constexpr (LPT == 3) asm volatile("s_waitcnt vmcnt(3)" ::: "memory");
    else                         asm volatile("s_waitcnt vmcnt(4)" ::: "memory");
  };

  stageA(Al[0], 0); stageB(Bl[0], 0);
  stageA(Al[1], 1); stageB(Bl[1], 1);
  waitLPT();
  BAR();

  f32x4 acc[4][NB] = {};

  for (int kt = 0; kt < NT; ++kt) {
    const bf16* Ac = Al[kt & 1];
    const bf16* Bc = Bl[kt & 1];

    bf16x8 af[4][2], bf[NB][2];
#pragma unroll
    for (int m = 0; m < 4; m++)
#pragma unroll
      for (int kk = 0; kk < 2; kk++)
        af[m][kk] = lds_frag(Ac, wm * 64 + m * 16 + lr, kk * 64 + lg * 16);
#pragma unroll
    for (int n = 0; n < NB; n++)
#pragma unroll
      for (int kk = 0; kk < 2; kk++)
        bf[n][kk] = lds_frag(Bc, wn * (BN / 4) + n * 16 + lr, kk * 64 + lg * 16);

    asm volatile("s_waitcnt lgkmcnt(0)" ::: "memory");
    __builtin_amdgcn_sched_barrier(0);
    BAR();

    if (kt + 2 < NT) {
      stageA(Al[kt & 1], kt + 2);
      stageB(Bl[kt & 1], kt + 2);
    }

    __builtin_amdgcn_s_setprio(1);
#pragma unroll
    for (int kk = 0; kk < 2; kk++)
#pragma unroll
      for (int m = 0; m < 4; m++)
#pragma unroll
        for (int n = 0; n < NB; n++)
          acc[m][n] = __builtin_amdgcn_mfma_f32_16x16x32_bf16(
              af[m][kk], bf[n][kk], acc[m][n], 0, 0, 0);
    __builtin_amdgcn_s_setprio(0);

    if (kt < NT - 2) waitLPT();
    else             asm volatile("s_waitcnt vmcnt(0)" ::: "memory");
    BAR();
  }

#pragma unroll
  for (int m = 0; m < 4; m++) {
    const int row = bm * 128 + wm * 64 + m * 16 + lg * 4;
#pragma unroll
    for (int n = 0; n < NB; n++) {
      const int col = bn * BN + wn * (BN / 4) + n * 16 + lr;
#pragma unroll
      for (int j = 0; j < 4; j++) {
        if constexpr (BF16OUT)
          Cb[(size_t)(row + j) * N_ + col] = (bf16)acc[m][n][j];
        else
          Cf[(size_t)(row + j) * N_ + col] = acc[m][n][j] + bias[col];
      }
    }
  }
}

// ---------------------------------------------------------------- attention v4 (R14 config)
// QBLK=128, 8 waves x 16 q-rows, swapped-operand S^T=mfma(K,Q), in-register P,
// V via ds_read_b64_tr_b16, 3-deep KV pipeline, vmcnt(2), defer-max (T13),
// XCD-aware block map (each XCD: 4 (b,h) pairs x 16 q-blocks -> 2 MB KV in L2).
__global__ __launch_bounds__(512, 4) void attn_kernel(const bf16* __restrict__ qkv,
                                                      bf16* __restrict__ out) {
  __shared__ bf16 Kl[3][64 * 64];
  __shared__ bf16 Vl[3][64 * 64];

  const int tid = threadIdx.x, w = tid >> 6, l = tid & 63;
  const int bid = blockIdx.x;
  const int x = bid & 7, ii = bid >> 3;
  const int bh = x * 4 + (ii >> 4);
  const int qb = ii & 15;
  const int b = bh >> 4, h = bh & 15;
  const int q0 = qb * 128;
  const int lr = l & 15, lg = l >> 4;
  const float SC = 0.18033688011f;   // 0.125 * log2(e)

  const char* qkv_b = (const char*)qkv + (size_t)(b * TT) * (QKVN * 2);

  size_t koff; u32 kdst;
  {
    const int R0 = 8 * w;
    const int r = R0 + (l >> 3);
    const int colb = (((l & 7) * 16) ^ (((l >> 3) & 7) << 4));
    koff = (size_t)r * (QKVN * 2) + (DIMC + h * HD) * 2 + colb;
    kdst = (u32)(R0 * 64);
  }
  size_t voff; u32 vdst;
  {
    const int c = tid;
    const int t = c >> 3, w_ = c & 7;
    const int kv = (t & 15) * 4 + (w_ >> 1);
    const int d  = (t >> 4) * 16 + (w_ & 1) * 8;
    voff = (size_t)kv * (QKVN * 2) + (2 * DIMC + h * HD + d) * 2;
    vdst = (u32)(w * 512);
  }

  auto stage = [&](int buf, int kb) {
    const char* rowb = qkv_b + (size_t)(kb * 64) * (QKVN * 2);
    gload16(rowb + koff, &Kl[buf][kdst]);
    gload16(rowb + voff, &Vl[buf][vdst]);
  };

  bf16x8 qf[2];
  {
    const bf16* qp = qkv + (size_t)(b * TT + q0 + w * 16 + lr) * QKVN + h * HD + lg * 8;
    qf[0] = *(const bf16x8*)qp;
    qf[1] = *(const bf16x8*)(qp + 32);
  }

  f32x4 Oa[4] = {};
  float mrow = -1e30f, lrow = 0.f;

  int kb0 = 2 * qb - 2; if (kb0 < 0) kb0 = 0;
  int kb1 = 2 * qb + 3; if (kb1 > 31) kb1 = 31;

  stage(0, kb0);
  stage(1, kb0 + 1);
  asm volatile("s_waitcnt vmcnt(2)" ::: "memory");
  BAR();

  for (int kb = kb0; kb <= kb1; ++kb) {
    const int c = (kb - kb0) % 3;
    if (kb + 2 <= kb1) stage((c + 2) % 3, kb + 2);

    const bf16* Kb = &Kl[c][0];
    f32x4 Sa[4] = {};
#pragma unroll
    for (int kf = 0; kf < 2; kf++)
#pragma unroll
      for (int nf = 0; nf < 4; nf++) {
        const char* kp = (const char*)Kb + (nf * 16 + lr) * 128
                         + ((kf * 64 + lg * 16) ^ ((lr & 7) << 4));
        bf16x8 kfr = *(const bf16x8*)kp;
        Sa[nf] = __builtin_amdgcn_mfma_f32_16x16x32_bf16(kfr, qf[kf], Sa[nf], 0, 0, 0);
      }

    bf16x4 tr0[4][2], tr1[4][2];
    {
      const u32 vbase = lds_u32(&Vl[c][0]) + l * 8;
#pragma unroll
      for (int nf = 0; nf < 4; nf++)
#pragma unroll
        for (int kf = 0; kf < 2; kf++) {
          const u32 a = vbase + (u32)((nf * 16 + kf * 8) * 128);
          asm volatile("ds_read_b64_tr_b16 %0, %1"
                       : "=v"(tr0[nf][kf]) : "v"(a));
          asm volatile("ds_read_b64_tr_b16 %0, %1 offset:512"
                       : "=v"(tr1[nf][kf]) : "v"(a));
        }
    }

    const int kvb = kb * 64;
    const int qrow = q0 + w * 16 + lr;
    float mblk = -1e30f;
#pragma unroll
    for (int nf = 0; nf < 4; nf++)
#pragma unroll
      for (int j = 0; j < 4; j++) {
        int kv = kvb + nf * 16 + lg * 4 + j;
        int dq = qrow - kv;
        float s = Sa[nf][j] * SC;
        if (dq > WINDOW || dq < -WINDOW) s = -1e30f;
        Sa[nf][j] = s;
        mblk = fmaxf(mblk, s);
      }
    mblk = fmaxf(mblk, __shfl_xor(mblk, 16));
    mblk = fmaxf(mblk, __shfl_xor(mblk, 32));

    if (!__all(mblk <= mrow + 8.f)) {
      float mn = fmaxf(mrow, mblk);
      float sc = exp2f(mrow - mn);
      mrow = mn;
      lrow *= sc;
#pragma unroll
      for (int j = 0; j < 4; j++) {
        float so = __shfl(sc, lg * 4 + j);
#pragma unroll
        for (int nf = 0; nf < 4; nf++) Oa[nf][j] *= so;
      }
    }

    float rsum = 0.f;
#pragma unroll
    for (int nf = 0; nf < 4; nf++)
#pragma unroll
      for (int j = 0; j < 4; j++) {
        float e = exp2f(Sa[nf][j] - mrow);
        Sa[nf][j] = e;
        rsum += e;
      }
    rsum += __shfl_xor(rsum, 16);
    rsum += __shfl_xor(rsum, 32);
    lrow += rsum;

    bf16x8 pa[2];
#pragma unroll
    for (int kf = 0; kf < 2; kf++)
#pragma unroll
      for (int e = 0; e < 4; e++) {
        pa[kf][e]     = (bf16)Sa[2 * kf][e];
        pa[kf][e + 4] = (bf16)Sa[2 * kf + 1][e];
      }

    asm volatile("s_waitcnt lgkmcnt(0)" ::: "memory");
    __builtin_amdgcn_sched_barrier(0);
#pragma unroll
    for (int nf = 0; nf < 4; nf++)
#pragma unroll
      for (int kf = 0; kf < 2; kf++) {
        bf16x8 vb;
#pragma unroll
        for (int e = 0; e < 4; e++) {
          vb[e]     = tr0[nf][kf][e];
          vb[e + 4] = tr1[nf][kf][e];
        }
        Oa[nf] = __builtin_amdgcn_mfma_f32_16x16x32_bf16(pa[kf], vb, Oa[nf], 0, 0, 0);
      }

    if (kb < kb1) {
      if (kb + 2 <= kb1) asm volatile("s_waitcnt vmcnt(2)" ::: "memory");
      else               asm volatile("s_waitcnt vmcnt(0)" ::: "memory");
    }
    BAR();
  }

  float lo[4];
#pragma unroll
  for (int j = 0; j < 4; j++) lo[j] = __shfl(lrow, lg * 4 + j);
#pragma unroll
  for (int nf = 0; nf < 4; nf++) {
#pragma unroll
    for (int j = 0; j < 4; j++) {
      int q = q0 + w * 16 + lg * 4 + j;
      int d = nf * 16 + lr;
      out[(size_t)(b * TT + q) * DIMC + h * HD + d] = (bf16)(Oa[nf][j] / lo[j]);
    }
  }
}

// ---------------------------------------------------------------- launch
extern "C" void kernel_launch(void* const* d_in, const int* in_sizes, int n_in,
                              void* d_out, int out_size, void* d_ws, size_t ws_size,
                              hipStream_t stream) {
  const float* x     = (const float*)d_in[0];
  const float* Wqkv  = (const float*)d_in[1];
  const float* Wproj = (const float*)d_in[2];
  const float* bproj = (const float*)d_in[3];
  float* out = (float*)d_out;

  char* ws = (char*)d_ws;
  bf16* xb   = (bf16*)(ws);
  bf16* wqb  = (bf16*)(ws + 8388608);
  bf16* wpb  = (bf16*)(ws + 14680064);
  bf16* qkvb = (bf16*)(ws + 16777216);
  bf16* aob  = (bf16*)(ws + 41943040);

  cast3_kernel<<<2048, 256, 0, stream>>>(x, Wqkv, Wproj, xb, wqb, wpb);
  gemm_kernel<192, QKVN, true><<<512, 512, 0, stream>>>(xb, wqb, qkvb, nullptr, nullptr);
  attn_kernel<<<512, 512, 0, stream>>>(qkvb, aob);
  gemm_kernel<64, DIMC, false><<<512, 512, 0, stream>>>(aob, wpb, nullptr, out, bproj);
}